// Round 8
// baseline (167.119 us; speedup 1.0000x reference)
//
#include <hip/hip_runtime.h>
#include <hip/hip_bf16.h>
#include <math.h>

// Router: logits = X @ W^T + b ; top-2 over 64 experts; softmax over the 2; rest 0.
// X: [32768,1024] f32, W: [64,1024] f32, b: [64] f32, Out: [32768,64] f32.
//
// MFMA path: exact bf16 hi/lo split, 3-term product (hh + hl + lh). Near-tie
// tokens (3rd logit within TAU of v2) recomputed exactly by rescue kernel.
//
// Round-7 change: occupancy fix. Rounds 5/6 were latency-bound at 8 waves/CU
// (2048 waves total, 20% occupancy; compiler re-rolls source pipelines, VGPR
// 60->40, so ILP is not available -> TLP must hide latency). New decomposition:
// block = 4 waves x 16 tokens, split-K 4-way (wave q does K in [q*256,q*256+256)),
// partials combined via 17-padded LDS scratch, wave q finalizes tokens r=q.
// Grid 2048 -> 8 blocks/CU x 4 waves = 32 waves/CU capacity.
//
// A/B k-mapping: element j of lane l covers k = (l>>4)*8 + j, identical for A
// (in-register split) and B (pack_w), so the k-sum is permutation-safe.
// C/D layout (m89-verified): col = lane&15, row = (lane>>4)*4 + reg.
//
// Requires ws_size >= 512 KB (cnt @0, list @256, Whi @256K, Wlo @384K).

typedef __attribute__((ext_vector_type(8))) short bf16x8;
typedef __attribute__((ext_vector_type(4))) float f32x4;

#define TOKENS 32768
#define DDIM   1024
#define KSTEPS 8          // per-wave K steps (split-K/4: 8 x 32 = 256)
#define TAU    1e-3f

#define WS_CNT_OFF   0
#define WS_LIST_OFF  256
#define WS_WHI_OFF   262144
#define WS_WLO_OFF   (262144 + 131072)

union FragU { bf16x8 v; unsigned int u[4]; };

__device__ inline unsigned int pk_bf16(float a, float b) {
    float2 f; f.x = a; f.y = b;
    __hip_bfloat162 h = __float22bfloat162_rn(f);
    union { __hip_bfloat162 h2; unsigned int u; } cv; cv.h2 = h;
    return cv.u;
}
__device__ inline float2 bf2f2(unsigned int u) {
    union { __hip_bfloat162 h2; unsigned int uu; } cv; cv.uu = u;
    return __bfloat1622float2(cv.h2);
}
__device__ inline void merge2(float& v1, int& i1, float& v2, int& i2,
                              float o1, int oi1, float o2, int oi2) {
    const bool b1 = (o1 > v1) || (o1 == v1 && oi1 < i1);
    if (b1) {
        const bool b2 = (v1 > o2) || (v1 == o2 && i1 < oi2);
        v2 = b2 ? v1 : o2;  i2 = b2 ? i1 : oi2;
        v1 = o1;            i1 = oi1;
    } else {
        const bool b2 = (o1 > v2) || (o1 == v2 && oi1 < i2);
        if (b2) { v2 = o1; i2 = oi1; }
    }
}

// ---- kernel 1: pack W into fragment-ordered bf16 hi/lo ----
__launch_bounds__(256)
__global__ void pack_w_kernel(const float* __restrict__ W,
                              unsigned int* __restrict__ Whi,
                              unsigned int* __restrict__ Wlo) {
    const int idx = blockIdx.x * 256 + threadIdx.x;     // 0..8191 = (s,n,l)
    const int l = idx & 63, n = (idx >> 6) & 3, s = idx >> 8;
    const int e  = n * 16 + (l & 15);
    const int k0 = s * 32 + (l >> 4) * 8;
    const float* p = W + e * DDIM + k0;
    const float4 a = *(const float4*)p;
    const float4 b = *(const float4*)(p + 4);
    const float f[8] = {a.x, a.y, a.z, a.w, b.x, b.y, b.z, b.w};
    unsigned int hu[4], lu[4];
    #pragma unroll
    for (int j = 0; j < 4; ++j) {
        const float x0 = f[2 * j], x1 = f[2 * j + 1];
        const unsigned int h = pk_bf16(x0, x1);
        const float2 hf = bf2f2(h);
        hu[j] = h;
        lu[j] = pk_bf16(x0 - hf.x, x1 - hf.y);
    }
    uint4 hv; hv.x = hu[0]; hv.y = hu[1]; hv.z = hu[2]; hv.w = hu[3];
    uint4 lv; lv.x = lu[0]; lv.y = lu[1]; lv.z = lu[2]; lv.w = lu[3];
    *(uint4*)(Whi + (size_t)idx * 4) = hv;
    *(uint4*)(Wlo + (size_t)idx * 4) = lv;
}

// ---- kernel 2: main MFMA router (split-K x4 per block) ----
__launch_bounds__(256, 6)
__global__ void router_mfma(const float* __restrict__ X,
                            const unsigned int* __restrict__ Whi,
                            const unsigned int* __restrict__ Wlo,
                            const float* __restrict__ Bv,
                            float* __restrict__ Out,
                            unsigned int* __restrict__ flagCnt,
                            int* __restrict__ flagList) {
    __shared__ float sScr[4][64][17];   // partial acc exchange, +1-pad -> conflict-free

    const int tid  = threadIdx.x;
    const int q    = tid >> 6;        // wave id = K-quarter AND finalize-reg r
    const int lane = tid & 63;
    const int rl   = lane & 15;       // A-row / B-col / C-col index
    const int kg   = lane >> 4;       // k-group
    const int tokBase = blockIdx.x * 16;

    const float* xp = X + (size_t)(tokBase + rl) * DDIM + q * 256 + kg * 8;
    const unsigned int* whp = Whi + (size_t)lane * 4;
    const unsigned int* wlp = Wlo + (size_t)lane * 4;
    const int q8 = q * KSTEPS;

    f32x4 acc[4] = {f32x4{0,0,0,0}, f32x4{0,0,0,0}, f32x4{0,0,0,0}, f32x4{0,0,0,0}};

    float4 xaA, xbA, xaB, xbB;
    FragU bhA[4], blA[4], bhB[4], blB[4];

#define LDX(s, xa, xb) { const float* p_ = xp + (s) * 32; \
        xa = *(const float4*)p_; xb = *(const float4*)(p_ + 4); }
#define LDW(s, bh, bl) { \
        _Pragma("unroll") for (int n_ = 0; n_ < 4; ++n_) { \
            const size_t off_ = (size_t)((((q8 + (s)) * 4 + n_) * 64)) * 4; \
            *(uint4*)&bh[n_].u[0] = *(const uint4*)(whp + off_); \
            *(uint4*)&bl[n_].u[0] = *(const uint4*)(wlp + off_); } }
#define CM(xa, xb, bh, bl) { \
        FragU ah_, al_; \
        const float fx_[8] = {xa.x, xa.y, xa.z, xa.w, xb.x, xb.y, xb.z, xb.w}; \
        _Pragma("unroll") for (int j_ = 0; j_ < 4; ++j_) { \
            const unsigned int h_ = pk_bf16(fx_[2*j_], fx_[2*j_+1]); \
            const float2 hf_ = bf2f2(h_); \
            ah_.u[j_] = h_; \
            al_.u[j_] = pk_bf16(fx_[2*j_] - hf_.x, fx_[2*j_+1] - hf_.y); } \
        _Pragma("unroll") for (int n_ = 0; n_ < 4; ++n_) { \
            acc[n_] = __builtin_amdgcn_mfma_f32_16x16x32_bf16(ah_.v, bh[n_].v, acc[n_], 0, 0, 0); \
            acc[n_] = __builtin_amdgcn_mfma_f32_16x16x32_bf16(ah_.v, bl[n_].v, acc[n_], 0, 0, 0); \
            acc[n_] = __builtin_amdgcn_mfma_f32_16x16x32_bf16(al_.v, bh[n_].v, acc[n_], 0, 0, 0); } }

    LDX(0, xaA, xbA); LDW(0, bhA, blA);
    LDX(1, xaB, xbB); LDW(1, bhB, blB);
    #pragma unroll 1
    for (int s = 0; s < KSTEPS; s += 2) {
        CM(xaA, xbA, bhA, blA);
        if (s + 2 < KSTEPS) { LDX(s + 2, xaA, xbA); LDW(s + 2, bhA, blA); }
        CM(xaB, xbB, bhB, blB);
        if (s + 3 < KSTEPS) { LDX(s + 3, xaB, xbB); LDW(s + 3, bhB, blB); }
    }
#undef LDX
#undef LDW
#undef CM

    // ---- cross-wave K-combine through padded LDS ----
    #pragma unroll
    for (int n = 0; n < 4; ++n)
        #pragma unroll
        for (int r = 0; r < 4; ++r)
            sScr[q][lane][n * 4 + r] = acc[n][r];
    __syncthreads();

    // Wave q finalizes the 4 tokens with reg index r = q (token = kg*4 + q).
    float v[4];
    #pragma unroll
    for (int n = 0; n < 4; ++n) {
        float s0 = sScr[0][lane][n * 4 + q];
        float s1 = sScr[1][lane][n * 4 + q];
        float s2 = sScr[2][lane][n * 4 + q];
        float s3 = sScr[3][lane][n * 4 + q];
        v[n] = (s0 + s1) + (s2 + s3) + Bv[n * 16 + rl];
    }

    // in-lane top-2 over this lane's 4 experts (e = n*16 + rl)
    float v1 = -INFINITY, v2 = -INFINITY;
    int i1 = 0x7fffffff, i2 = 0x7fffffff;
    #pragma unroll
    for (int n = 0; n < 4; ++n) {
        const float val = v[n];
        const int   e   = n * 16 + rl;
        if (val > v1 || (val == v1 && e < i1)) { v2 = v1; i2 = i1; v1 = val; i1 = e; }
        else if (val > v2 || (val == v2 && e < i2)) { v2 = val; i2 = e; }
    }
    // butterfly across the 16 lanes of this kg group (lex: value desc, idx asc)
    #pragma unroll
    for (int st = 1; st <= 8; st <<= 1) {
        const float o1 = __shfl_xor(v1, st); const int oi1 = __shfl_xor(i1, st);
        const float o2 = __shfl_xor(v2, st); const int oi2 = __shfl_xor(i2, st);
        merge2(v1, i1, v2, i2, o1, oi1, o2, oi2);
    }
    // near-tie flag: any 3rd logit within TAU of v2?
    int cnt = 0;
    #pragma unroll
    for (int n = 0; n < 4; ++n) cnt += (v[n] > v2 - TAU) ? 1 : 0;
    cnt += __shfl_xor(cnt, 1);
    cnt += __shfl_xor(cnt, 2);
    cnt += __shfl_xor(cnt, 4);
    cnt += __shfl_xor(cnt, 8);

    const int T = tokBase + kg * 4 + q;
    if (rl == 0 && cnt > 2) {
        const unsigned int pos = atomicAdd(flagCnt, 1u);
        if (pos < TOKENS) flagList[pos] = T;
    }
    const float ex = expf(v2 - v1);      // <= 1
    const float w1 = 1.f / (1.f + ex);
    const float w2 = ex * w1;
    const int e0 = rl * 4;
    float4 o;
    o.x = (e0 + 0 == i1) ? w1 : ((e0 + 0 == i2) ? w2 : 0.f);
    o.y = (e0 + 1 == i1) ? w1 : ((e0 + 1 == i2) ? w2 : 0.f);
    o.z = (e0 + 2 == i1) ? w1 : ((e0 + 2 == i2) ? w2 : 0.f);
    o.w = (e0 + 3 == i1) ? w1 : ((e0 + 3 == i2) ? w2 : 0.f);
    *(float4*)(Out + (size_t)T * 64 + e0) = o;
}

// ---- kernel 3: exact fp32 rescue for near-tie tokens ----
__launch_bounds__(64)
__global__ void rescue_kernel(const float* __restrict__ X,
                              const float* __restrict__ W,
                              const float* __restrict__ Bv,
                              float* __restrict__ Out,
                              const unsigned int* __restrict__ flagCnt,
                              const int* __restrict__ flagList) {
    __shared__ float sx[DDIM];
    const int lane = threadIdx.x;
    unsigned int n = *flagCnt;
    if (n > TOKENS) n = TOKENS;
    for (unsigned int i = blockIdx.x; i < n; i += gridDim.x) {
        const int t = flagList[i];
        __syncthreads();
        #pragma unroll
        for (int k = 0; k < 4; ++k)
            ((float4*)sx)[lane + 64 * k] =
                ((const float4*)(X + (size_t)t * DDIM))[lane + 64 * k];
        __syncthreads();
        float acc = Bv[lane];
        const float* wr = W + (size_t)lane * DDIM;
        #pragma unroll 4
        for (int d = 0; d < DDIM; d += 4) {
            const float4 wv = *(const float4*)(wr + d);
            acc = fmaf(sx[d + 0], wv.x, acc);
            acc = fmaf(sx[d + 1], wv.y, acc);
            acc = fmaf(sx[d + 2], wv.z, acc);
            acc = fmaf(sx[d + 3], wv.w, acc);
        }
        float v1 = acc, v2 = -INFINITY;
        int i1 = lane, i2 = 0x7fffffff;
        #pragma unroll
        for (int st = 1; st <= 32; st <<= 1) {
            const float o1 = __shfl_xor(v1, st); const int oi1 = __shfl_xor(i1, st);
            const float o2 = __shfl_xor(v2, st); const int oi2 = __shfl_xor(i2, st);
            merge2(v1, i1, v2, i2, o1, oi1, o2, oi2);
        }
        const float ex = expf(v2 - v1);
        const float w1 = 1.f / (1.f + ex);
        const float w2 = ex * w1;
        Out[(size_t)t * 64 + lane] = (lane == i1) ? w1 : ((lane == i2) ? w2 : 0.f);
    }
}

extern "C" void kernel_launch(void* const* d_in, const int* in_sizes, int n_in,
                              void* d_out, int out_size, void* d_ws, size_t ws_size,
                              hipStream_t stream) {
    const float* X  = (const float*)d_in[0];   // [32768, 1024]
    const float* W  = (const float*)d_in[1];   // [64, 1024]
    const float* Bv = (const float*)d_in[2];   // [64]
    float* Out = (float*)d_out;                // [32768, 64]

    unsigned char* ws = (unsigned char*)d_ws;
    unsigned int* cnt  = (unsigned int*)(ws + WS_CNT_OFF);
    int*          list = (int*)(ws + WS_LIST_OFF);
    unsigned int* Whi  = (unsigned int*)(ws + WS_WHI_OFF);
    unsigned int* Wlo  = (unsigned int*)(ws + WS_WLO_OFF);

    hipMemsetAsync(cnt, 0, 4, stream);
    hipLaunchKernelGGL(pack_w_kernel, dim3(32), dim3(256), 0, stream, W, Whi, Wlo);
    hipLaunchKernelGGL(router_mfma, dim3(TOKENS / 16), dim3(256), 0, stream,
                       X, Whi, Wlo, Bv, Out, cnt, list);
    hipLaunchKernelGGL(rescue_kernel, dim3(512), dim3(64), 0, stream,
                       X, W, Bv, Out, cnt, list);
}

// Round 9
// 79.404 us; speedup vs baseline: 2.1047x; 2.1047x over previous
//
#include <hip/hip_runtime.h>
#include <hip/hip_bf16.h>
#include <math.h>

// Router: logits = X @ W^T + b ; top-2 over 64 experts; softmax over the 2; rest 0.
// X: [32768,1024] f32, W: [64,1024] f32, b: [64] f32, Out: [32768,64] f32.
//
// MFMA path: exact bf16 hi/lo split, 3-term product (hh + hl + lh). Near-tie
// tokens (3rd logit within TAU of v2) recomputed exactly by rescue kernel.
//
// Round-9 change: fix round-8's spill. (256,6) capped VGPR at ~80 < the ~96+
// the K-loop state needs -> acc/W-frags spilled to scratch (WRITE_SIZE 8MB ->
// 356MB, FETCH +96MB readback, dur 167us). (256,4) caps at 128 >> compiler's
// natural ~60 for this structure (round 5 evidence). Occupancy then grid-
// limited: 8 blocks/CU x 4 waves = 32 waves/CU, grid 2048 = exactly 8/CU.
//
// Decomposition (round 7/8): block = 4 waves x 16 tokens, split-K 4-way
// (wave q owns K in [q*256, q*256+256)); partials combined via 17-padded LDS;
// wave q finalizes the 4 tokens with acc reg index r=q.
//
// A/B k-mapping: element j of lane l covers k = (l>>4)*8 + j, identical for A
// (in-register split) and B (pack_w), so the k-sum is permutation-safe.
// C/D layout (m89-verified): col = lane&15, row = (lane>>4)*4 + reg.
//
// Requires ws_size >= 512 KB (cnt @0, list @256, Whi @256K, Wlo @384K).

typedef __attribute__((ext_vector_type(8))) short bf16x8;
typedef __attribute__((ext_vector_type(4))) float f32x4;

#define TOKENS 32768
#define DDIM   1024
#define KSTEPS 8          // per-wave K steps (split-K/4: 8 x 32 = 256)
#define TAU    1e-3f

#define WS_CNT_OFF   0
#define WS_LIST_OFF  256
#define WS_WHI_OFF   262144
#define WS_WLO_OFF   (262144 + 131072)

union FragU { bf16x8 v; unsigned int u[4]; };

__device__ inline unsigned int pk_bf16(float a, float b) {
    float2 f; f.x = a; f.y = b;
    __hip_bfloat162 h = __float22bfloat162_rn(f);
    union { __hip_bfloat162 h2; unsigned int u; } cv; cv.h2 = h;
    return cv.u;
}
__device__ inline float2 bf2f2(unsigned int u) {
    union { __hip_bfloat162 h2; unsigned int uu; } cv; cv.uu = u;
    return __bfloat1622float2(cv.h2);
}
__device__ inline void merge2(float& v1, int& i1, float& v2, int& i2,
                              float o1, int oi1, float o2, int oi2) {
    const bool b1 = (o1 > v1) || (o1 == v1 && oi1 < i1);
    if (b1) {
        const bool b2 = (v1 > o2) || (v1 == o2 && i1 < oi2);
        v2 = b2 ? v1 : o2;  i2 = b2 ? i1 : oi2;
        v1 = o1;            i1 = oi1;
    } else {
        const bool b2 = (o1 > v2) || (o1 == v2 && oi1 < i2);
        if (b2) { v2 = o1; i2 = oi1; }
    }
}

// ---- kernel 1: pack W into fragment-ordered bf16 hi/lo ----
__launch_bounds__(256)
__global__ void pack_w_kernel(const float* __restrict__ W,
                              unsigned int* __restrict__ Whi,
                              unsigned int* __restrict__ Wlo) {
    const int idx = blockIdx.x * 256 + threadIdx.x;     // 0..8191 = (s,n,l)
    const int l = idx & 63, n = (idx >> 6) & 3, s = idx >> 8;
    const int e  = n * 16 + (l & 15);
    const int k0 = s * 32 + (l >> 4) * 8;
    const float* p = W + e * DDIM + k0;
    const float4 a = *(const float4*)p;
    const float4 b = *(const float4*)(p + 4);
    const float f[8] = {a.x, a.y, a.z, a.w, b.x, b.y, b.z, b.w};
    unsigned int hu[4], lu[4];
    #pragma unroll
    for (int j = 0; j < 4; ++j) {
        const float x0 = f[2 * j], x1 = f[2 * j + 1];
        const unsigned int h = pk_bf16(x0, x1);
        const float2 hf = bf2f2(h);
        hu[j] = h;
        lu[j] = pk_bf16(x0 - hf.x, x1 - hf.y);
    }
    uint4 hv; hv.x = hu[0]; hv.y = hu[1]; hv.z = hu[2]; hv.w = hu[3];
    uint4 lv; lv.x = lu[0]; lv.y = lu[1]; lv.z = lu[2]; lv.w = lu[3];
    *(uint4*)(Whi + (size_t)idx * 4) = hv;
    *(uint4*)(Wlo + (size_t)idx * 4) = lv;
}

// ---- kernel 2: main MFMA router (split-K x4 per block) ----
__launch_bounds__(256, 4)
__global__ void router_mfma(const float* __restrict__ X,
                            const unsigned int* __restrict__ Whi,
                            const unsigned int* __restrict__ Wlo,
                            const float* __restrict__ Bv,
                            float* __restrict__ Out,
                            unsigned int* __restrict__ flagCnt,
                            int* __restrict__ flagList) {
    __shared__ float sScr[4][64][17];   // partial acc exchange, +1-pad -> conflict-free

    const int tid  = threadIdx.x;
    const int q    = tid >> 6;        // wave id = K-quarter AND finalize-reg r
    const int lane = tid & 63;
    const int rl   = lane & 15;       // A-row / B-col / C-col index
    const int kg   = lane >> 4;       // k-group
    const int tokBase = blockIdx.x * 16;

    const float* xp = X + (size_t)(tokBase + rl) * DDIM + q * 256 + kg * 8;
    const unsigned int* whp = Whi + (size_t)lane * 4;
    const unsigned int* wlp = Wlo + (size_t)lane * 4;
    const int q8 = q * KSTEPS;

    f32x4 acc[4] = {f32x4{0,0,0,0}, f32x4{0,0,0,0}, f32x4{0,0,0,0}, f32x4{0,0,0,0}};

    float4 xaA, xbA, xaB, xbB;
    FragU bhA[4], blA[4], bhB[4], blB[4];

#define LDX(s, xa, xb) { const float* p_ = xp + (s) * 32; \
        xa = *(const float4*)p_; xb = *(const float4*)(p_ + 4); }
#define LDW(s, bh, bl) { \
        _Pragma("unroll") for (int n_ = 0; n_ < 4; ++n_) { \
            const size_t off_ = (size_t)((((q8 + (s)) * 4 + n_) * 64)) * 4; \
            *(uint4*)&bh[n_].u[0] = *(const uint4*)(whp + off_); \
            *(uint4*)&bl[n_].u[0] = *(const uint4*)(wlp + off_); } }
#define CM(xa, xb, bh, bl) { \
        FragU ah_, al_; \
        const float fx_[8] = {xa.x, xa.y, xa.z, xa.w, xb.x, xb.y, xb.z, xb.w}; \
        _Pragma("unroll") for (int j_ = 0; j_ < 4; ++j_) { \
            const unsigned int h_ = pk_bf16(fx_[2*j_], fx_[2*j_+1]); \
            const float2 hf_ = bf2f2(h_); \
            ah_.u[j_] = h_; \
            al_.u[j_] = pk_bf16(fx_[2*j_] - hf_.x, fx_[2*j_+1] - hf_.y); } \
        _Pragma("unroll") for (int n_ = 0; n_ < 4; ++n_) { \
            acc[n_] = __builtin_amdgcn_mfma_f32_16x16x32_bf16(ah_.v, bh[n_].v, acc[n_], 0, 0, 0); \
            acc[n_] = __builtin_amdgcn_mfma_f32_16x16x32_bf16(ah_.v, bl[n_].v, acc[n_], 0, 0, 0); \
            acc[n_] = __builtin_amdgcn_mfma_f32_16x16x32_bf16(al_.v, bh[n_].v, acc[n_], 0, 0, 0); } }

    LDX(0, xaA, xbA); LDW(0, bhA, blA);
    LDX(1, xaB, xbB); LDW(1, bhB, blB);
    #pragma unroll 1
    for (int s = 0; s < KSTEPS; s += 2) {
        CM(xaA, xbA, bhA, blA);
        if (s + 2 < KSTEPS) { LDX(s + 2, xaA, xbA); LDW(s + 2, bhA, blA); }
        CM(xaB, xbB, bhB, blB);
        if (s + 3 < KSTEPS) { LDX(s + 3, xaB, xbB); LDW(s + 3, bhB, blB); }
    }
#undef LDX
#undef LDW
#undef CM

    // ---- cross-wave K-combine through padded LDS ----
    #pragma unroll
    for (int n = 0; n < 4; ++n)
        #pragma unroll
        for (int r = 0; r < 4; ++r)
            sScr[q][lane][n * 4 + r] = acc[n][r];
    __syncthreads();

    // Wave q finalizes the 4 tokens with reg index r = q (token = kg*4 + q).
    float v[4];
    #pragma unroll
    for (int n = 0; n < 4; ++n) {
        float s0 = sScr[0][lane][n * 4 + q];
        float s1 = sScr[1][lane][n * 4 + q];
        float s2 = sScr[2][lane][n * 4 + q];
        float s3 = sScr[3][lane][n * 4 + q];
        v[n] = (s0 + s1) + (s2 + s3) + Bv[n * 16 + rl];
    }

    // in-lane top-2 over this lane's 4 experts (e = n*16 + rl)
    float v1 = -INFINITY, v2 = -INFINITY;
    int i1 = 0x7fffffff, i2 = 0x7fffffff;
    #pragma unroll
    for (int n = 0; n < 4; ++n) {
        const float val = v[n];
        const int   e   = n * 16 + rl;
        if (val > v1 || (val == v1 && e < i1)) { v2 = v1; i2 = i1; v1 = val; i1 = e; }
        else if (val > v2 || (val == v2 && e < i2)) { v2 = val; i2 = e; }
    }
    // butterfly across the 16 lanes of this kg group (lex: value desc, idx asc)
    #pragma unroll
    for (int st = 1; st <= 8; st <<= 1) {
        const float o1 = __shfl_xor(v1, st); const int oi1 = __shfl_xor(i1, st);
        const float o2 = __shfl_xor(v2, st); const int oi2 = __shfl_xor(i2, st);
        merge2(v1, i1, v2, i2, o1, oi1, o2, oi2);
    }
    // near-tie flag: any 3rd logit within TAU of v2?
    int cnt = 0;
    #pragma unroll
    for (int n = 0; n < 4; ++n) cnt += (v[n] > v2 - TAU) ? 1 : 0;
    cnt += __shfl_xor(cnt, 1);
    cnt += __shfl_xor(cnt, 2);
    cnt += __shfl_xor(cnt, 4);
    cnt += __shfl_xor(cnt, 8);

    const int T = tokBase + kg * 4 + q;
    if (rl == 0 && cnt > 2) {
        const unsigned int pos = atomicAdd(flagCnt, 1u);
        if (pos < TOKENS) flagList[pos] = T;
    }
    const float ex = expf(v2 - v1);      // <= 1
    const float w1 = 1.f / (1.f + ex);
    const float w2 = ex * w1;
    const int e0 = rl * 4;
    float4 o;
    o.x = (e0 + 0 == i1) ? w1 : ((e0 + 0 == i2) ? w2 : 0.f);
    o.y = (e0 + 1 == i1) ? w1 : ((e0 + 1 == i2) ? w2 : 0.f);
    o.z = (e0 + 2 == i1) ? w1 : ((e0 + 2 == i2) ? w2 : 0.f);
    o.w = (e0 + 3 == i1) ? w1 : ((e0 + 3 == i2) ? w2 : 0.f);
    *(float4*)(Out + (size_t)T * 64 + e0) = o;
}

// ---- kernel 3: exact fp32 rescue for near-tie tokens ----
__launch_bounds__(64)
__global__ void rescue_kernel(const float* __restrict__ X,
                              const float* __restrict__ W,
                              const float* __restrict__ Bv,
                              float* __restrict__ Out,
                              const unsigned int* __restrict__ flagCnt,
                              const int* __restrict__ flagList) {
    __shared__ float sx[DDIM];
    const int lane = threadIdx.x;
    unsigned int n = *flagCnt;
    if (n > TOKENS) n = TOKENS;
    for (unsigned int i = blockIdx.x; i < n; i += gridDim.x) {
        const int t = flagList[i];
        __syncthreads();
        #pragma unroll
        for (int k = 0; k < 4; ++k)
            ((float4*)sx)[lane + 64 * k] =
                ((const float4*)(X + (size_t)t * DDIM))[lane + 64 * k];
        __syncthreads();
        float acc = Bv[lane];
        const float* wr = W + (size_t)lane * DDIM;
        #pragma unroll 4
        for (int d = 0; d < DDIM; d += 4) {
            const float4 wv = *(const float4*)(wr + d);
            acc = fmaf(sx[d + 0], wv.x, acc);
            acc = fmaf(sx[d + 1], wv.y, acc);
            acc = fmaf(sx[d + 2], wv.z, acc);
            acc = fmaf(sx[d + 3], wv.w, acc);
        }
        float v1 = acc, v2 = -INFINITY;
        int i1 = lane, i2 = 0x7fffffff;
        #pragma unroll
        for (int st = 1; st <= 32; st <<= 1) {
            const float o1 = __shfl_xor(v1, st); const int oi1 = __shfl_xor(i1, st);
            const float o2 = __shfl_xor(v2, st); const int oi2 = __shfl_xor(i2, st);
            merge2(v1, i1, v2, i2, o1, oi1, o2, oi2);
        }
        const float ex = expf(v2 - v1);
        const float w1 = 1.f / (1.f + ex);
        const float w2 = ex * w1;
        Out[(size_t)t * 64 + lane] = (lane == i1) ? w1 : ((lane == i2) ? w2 : 0.f);
    }
}

extern "C" void kernel_launch(void* const* d_in, const int* in_sizes, int n_in,
                              void* d_out, int out_size, void* d_ws, size_t ws_size,
                              hipStream_t stream) {
    const float* X  = (const float*)d_in[0];   // [32768, 1024]
    const float* W  = (const float*)d_in[1];   // [64, 1024]
    const float* Bv = (const float*)d_in[2];   // [64]
    float* Out = (float*)d_out;                // [32768, 64]

    unsigned char* ws = (unsigned char*)d_ws;
    unsigned int* cnt  = (unsigned int*)(ws + WS_CNT_OFF);
    int*          list = (int*)(ws + WS_LIST_OFF);
    unsigned int* Whi  = (unsigned int*)(ws + WS_WHI_OFF);
    unsigned int* Wlo  = (unsigned int*)(ws + WS_WLO_OFF);

    hipMemsetAsync(cnt, 0, 4, stream);
    hipLaunchKernelGGL(pack_w_kernel, dim3(32), dim3(256), 0, stream, W, Whi, Wlo);
    hipLaunchKernelGGL(router_mfma, dim3(TOKENS / 16), dim3(256), 0, stream,
                       X, Whi, Wlo, Bv, Out, cnt, list);
    hipLaunchKernelGGL(rescue_kernel, dim3(512), dim3(64), 0, stream,
                       X, W, Bv, Out, cnt, list);
}

// Round 10
// 74.806 us; speedup vs baseline: 2.2340x; 1.0615x over previous
//
#include <hip/hip_runtime.h>
#include <hip/hip_bf16.h>
#include <math.h>

// Router: logits = X @ W^T + b ; top-2 over 64 experts; softmax over the 2; rest 0.
// X: [32768,1024] f32, W: [64,1024] f32, b: [64] f32, Out: [32768,64] f32.
//
// MFMA path: exact bf16 hi/lo split, 3-term product (hh + hl + lh). Near-tie
// tokens (3rd logit within TAU of v2) recomputed exactly by rescue kernel.
//
// Round-10 change: kill the per-step vmcnt drains. X is staged via
// global_load_lds (fire-and-forget: no VGPR dest -> compiler cannot re-roll)
// into a per-wave 4-buffer LDS ring, with inline-asm COUNTED s_waitcnt vmcnt
// (12,12,12,12,12,10,8,0 across the 8 K-steps; never 0 until the tail) and
// sched_barrier(0) pinning the issue bundles so the FIFO counts are exact.
// W is double-buffered in VGPRs one step ahead; the same vmcnt(12) covers it.
// X fragment ds_reads use an XOR source-swizzle (pre-swizzled GLOBAL address,
// linear LDS dest) -> b128 reads at exact minimum bank traffic.
//
// Block = 512 thr / 8 waves = 32 tokens; wave (m = w&1 token half, q = w>>1
// K-quarter). Grid 1024. LDS 64 KB ring (combine scratch aliased) -> 2
// blocks/CU = 16 waves/CU; VGPR ~115 under launch_bounds(512,4) cap 128.
//
// A/B k-mapping: element j of lane l covers k = (l>>4)*8 + j, identical for A
// (in-register split) and B (pack_w), so the k-sum is permutation-safe.
// C/D layout (m89-verified): col = lane&15, row = (lane>>4)*4 + reg.
//
// Requires ws_size >= 512 KB (cnt @0, list @256, Whi @256K, Wlo @384K).

typedef __attribute__((ext_vector_type(8))) short bf16x8;
typedef __attribute__((ext_vector_type(4))) float f32x4;

#define TOKENS 32768
#define DDIM   1024
#define TAU    1e-3f

#define WS_CNT_OFF   0
#define WS_LIST_OFF  256
#define WS_WHI_OFF   262144
#define WS_WLO_OFF   (262144 + 131072)

#define AS1 __attribute__((address_space(1)))
#define AS3 __attribute__((address_space(3)))

union FragU { bf16x8 v; unsigned int u[4]; };

__device__ inline unsigned int pk_bf16(float a, float b) {
    float2 f; f.x = a; f.y = b;
    __hip_bfloat162 h = __float22bfloat162_rn(f);
    union { __hip_bfloat162 h2; unsigned int u; } cv; cv.h2 = h;
    return cv.u;
}
__device__ inline float2 bf2f2(unsigned int u) {
    union { __hip_bfloat162 h2; unsigned int uu; } cv; cv.uu = u;
    return __bfloat1622float2(cv.h2);
}
__device__ inline void merge2(float& v1, int& i1, float& v2, int& i2,
                              float o1, int oi1, float o2, int oi2) {
    const bool b1 = (o1 > v1) || (o1 == v1 && oi1 < i1);
    if (b1) {
        const bool b2 = (v1 > o2) || (v1 == o2 && i1 < oi2);
        v2 = b2 ? v1 : o2;  i2 = b2 ? i1 : oi2;
        v1 = o1;            i1 = oi1;
    } else {
        const bool b2 = (o1 > v2) || (o1 == v2 && oi1 < i2);
        if (b2) { v2 = o1; i2 = oi1; }
    }
}

// ---- kernel 1: pack W into fragment-ordered bf16 hi/lo ----
__launch_bounds__(256)
__global__ void pack_w_kernel(const float* __restrict__ W,
                              unsigned int* __restrict__ Whi,
                              unsigned int* __restrict__ Wlo) {
    const int idx = blockIdx.x * 256 + threadIdx.x;     // 0..8191 = (s,n,l)
    const int l = idx & 63, n = (idx >> 6) & 3, s = idx >> 8;
    const int e  = n * 16 + (l & 15);
    const int k0 = s * 32 + (l >> 4) * 8;
    const float* p = W + e * DDIM + k0;
    const float4 a = *(const float4*)p;
    const float4 b = *(const float4*)(p + 4);
    const float f[8] = {a.x, a.y, a.z, a.w, b.x, b.y, b.z, b.w};
    unsigned int hu[4], lu[4];
    #pragma unroll
    for (int j = 0; j < 4; ++j) {
        const float x0 = f[2 * j], x1 = f[2 * j + 1];
        const unsigned int h = pk_bf16(x0, x1);
        const float2 hf = bf2f2(h);
        hu[j] = h;
        lu[j] = pk_bf16(x0 - hf.x, x1 - hf.y);
    }
    uint4 hv; hv.x = hu[0]; hv.y = hu[1]; hv.z = hu[2]; hv.w = hu[3];
    uint4 lv; lv.x = lu[0]; lv.y = lu[1]; lv.z = lu[2]; lv.w = lu[3];
    *(uint4*)(Whi + (size_t)idx * 4) = hv;
    *(uint4*)(Wlo + (size_t)idx * 4) = lv;
}

// ---- kernel 2: main MFMA router (split-K x4, LDS-ring X staging) ----
__launch_bounds__(512, 4)
__global__ void router_mfma(const float* __restrict__ X,
                            const unsigned int* __restrict__ Whi,
                            const unsigned int* __restrict__ Wlo,
                            const float* __restrict__ Bv,
                            float* __restrict__ Out,
                            unsigned int* __restrict__ flagCnt,
                            int* __restrict__ flagList) {
    __shared__ __align__(16) char smem[8 * 4 * 2048];    // 64 KB: 8 waves x 4-buf ring
    float (*sScr)[64][17] = (float (*)[64][17])smem;     // aliased after the K-loop

    const int tid  = threadIdx.x;
    const int w    = tid >> 6;
    const int lane = tid & 63;
    const int m    = w & 1;          // token half (0/1)
    const int q    = w >> 1;         // K quarter (0..3)
    const int rl   = lane & 15;      // A-row / B-col / C-col index
    const int kg   = lane >> 4;      // k-group
    const int tokBase = blockIdx.x * 32;

    char* ringw = smem + w * 8192;   // wave-private ring (uniform per wave)

    // --- stage source (pre-swizzled global address; linear LDS dest) ---
    // lane l, inst i covers LDS bytes i*1024 + l*16 = data[row][colblk^ (row&7)]
    // with row = i*8 + (l>>3), so load data[row][cb] where cb = (l&7)^((l>>3)&7).
    const int cb   = (lane & 7) ^ ((lane >> 3) & 7);
    const int row0 = lane >> 3;
    const float* xsrc0 = X + (size_t)(tokBase + m * 16 + row0) * DDIM + q * 256 + cb * 4;
    const float* xsrc1 = xsrc0 + (size_t)8 * DDIM;

    // --- swizzled ds_read offsets for the A fragment (rows rl, colblks 2kg,2kg+1)
    const int dso0 = rl * 128 + (((kg * 2 + 0) ^ (rl & 7)) * 16);
    const int dso1 = rl * 128 + (((kg * 2 + 1) ^ (rl & 7)) * 16);

    const unsigned int* whp = Whi + (size_t)lane * 4;
    const unsigned int* wlp = Wlo + (size_t)lane * 4;
    const int q8 = q * 8;

    f32x4 acc[4] = {f32x4{0,0,0,0}, f32x4{0,0,0,0}, f32x4{0,0,0,0}, f32x4{0,0,0,0}};
    FragU WhA[4], WlA[4], WhB[4], WlB[4];

#define STAGE(s) do { \
        char* ld_ = ringw + (((s) & 3) * 2048); \
        __builtin_amdgcn_global_load_lds((AS1 const void*)(xsrc0 + (s) * 32), \
                                         (AS3 void*)(ld_),        16, 0, 0); \
        __builtin_amdgcn_global_load_lds((AS1 const void*)(xsrc1 + (s) * 32), \
                                         (AS3 void*)(ld_ + 1024), 16, 0, 0); \
    } while (0)

#define LDW(s, Wh, Wl) do { \
        _Pragma("unroll") for (int n_ = 0; n_ < 4; ++n_) { \
            const size_t off_ = (size_t)((((q8 + (s)) * 4 + n_) * 64)) * 4; \
            *(uint4*)&Wh[n_].u[0] = *(const uint4*)(whp + off_); \
            *(uint4*)&Wl[n_].u[0] = *(const uint4*)(wlp + off_); } \
    } while (0)

#define WAITVM(N) asm volatile("s_waitcnt vmcnt(" #N ")" ::: "memory")
#define SB() __builtin_amdgcn_sched_barrier(0)

#define COMPUTE(s, Wh, Wl) do { \
        const char* bb_ = ringw + (((s) & 3) * 2048); \
        const float4 x0_ = *(const float4*)(bb_ + dso0); \
        const float4 x1_ = *(const float4*)(bb_ + dso1); \
        FragU ah_, al_; \
        const float fx_[8] = {x0_.x, x0_.y, x0_.z, x0_.w, x1_.x, x1_.y, x1_.z, x1_.w}; \
        _Pragma("unroll") for (int j_ = 0; j_ < 4; ++j_) { \
            const unsigned int h_ = pk_bf16(fx_[2*j_], fx_[2*j_+1]); \
            const float2 hf_ = bf2f2(h_); \
            ah_.u[j_] = h_; \
            al_.u[j_] = pk_bf16(fx_[2*j_] - hf_.x, fx_[2*j_+1] - hf_.y); } \
        _Pragma("unroll") for (int n_ = 0; n_ < 4; ++n_) { \
            acc[n_] = __builtin_amdgcn_mfma_f32_16x16x32_bf16(ah_.v, Wh[n_].v, acc[n_], 0, 0, 0); \
            acc[n_] = __builtin_amdgcn_mfma_f32_16x16x32_bf16(ah_.v, Wl[n_].v, acc[n_], 0, 0, 0); \
            acc[n_] = __builtin_amdgcn_mfma_f32_16x16x32_bf16(al_.v, Wh[n_].v, acc[n_], 0, 0, 0); } \
    } while (0)

// body(s): issue next-W, then next+3 stage, then counted wait, then consume s.
#define BODY(s, VC, WhC, WlC, WhN, WlN) do { \
        if ((s) + 1 < 8) LDW((s) + 1, WhN, WlN); \
        SB(); \
        if ((s) + 3 < 8) STAGE((s) + 3); \
        SB(); \
        WAITVM(VC); \
        SB(); \
        COMPUTE(s, WhC, WlC); \
    } while (0)

    // Prologue: X(0), X(1) older than W(0); X(2) younger.
    STAGE(0); STAGE(1); SB();
    LDW(0, WhA, WlA);  SB();
    STAGE(2);          SB();

    // FIFO-derived counts: allowed outstanding after wait at body(s) =
    // stage(s+2) [2] + W(s+1) [8] + stage(s+3) [2], with tail guards.
    BODY(0, 12, WhA, WlA, WhB, WlB);
    BODY(1, 12, WhB, WlB, WhA, WlA);
    BODY(2, 12, WhA, WlA, WhB, WlB);
    BODY(3, 12, WhB, WlB, WhA, WlA);
    BODY(4, 12, WhA, WlA, WhB, WlB);
    BODY(5, 10, WhB, WlB, WhA, WlA);
    BODY(6,  8, WhA, WlA, WhB, WlB);
    BODY(7,  0, WhB, WlB, WhA, WlA);

#undef STAGE
#undef LDW
#undef WAITVM
#undef SB
#undef COMPUTE
#undef BODY

    // ---- cross-wave K-combine through padded LDS (aliased over the ring) ----
    __syncthreads();   // all waves: DMA drained (vmcnt(0) at body 7) + reads done
    #pragma unroll
    for (int n = 0; n < 4; ++n)
        #pragma unroll
        for (int r = 0; r < 4; ++r)
            sScr[w][lane][n * 4 + r] = acc[n][r];
    __syncthreads();

    // Wave (m,q) finalizes tokens kg*4 + q of token-half m.
    float v[4];
    #pragma unroll
    for (int n = 0; n < 4; ++n) {
        float s0 = sScr[(0 << 1) | m][lane][n * 4 + q];
        float s1 = sScr[(1 << 1) | m][lane][n * 4 + q];
        float s2 = sScr[(2 << 1) | m][lane][n * 4 + q];
        float s3 = sScr[(3 << 1) | m][lane][n * 4 + q];
        v[n] = (s0 + s1) + (s2 + s3) + Bv[n * 16 + rl];
    }

    // in-lane top-2 over this lane's 4 experts (e = n*16 + rl)
    float v1 = -INFINITY, v2 = -INFINITY;
    int i1 = 0x7fffffff, i2 = 0x7fffffff;
    #pragma unroll
    for (int n = 0; n < 4; ++n) {
        const float val = v[n];
        const int   e   = n * 16 + rl;
        if (val > v1 || (val == v1 && e < i1)) { v2 = v1; i2 = i1; v1 = val; i1 = e; }
        else if (val > v2 || (val == v2 && e < i2)) { v2 = val; i2 = e; }
    }
    // butterfly across the 16 lanes of this kg group (lex: value desc, idx asc)
    #pragma unroll
    for (int st = 1; st <= 8; st <<= 1) {
        const float o1 = __shfl_xor(v1, st); const int oi1 = __shfl_xor(i1, st);
        const float o2 = __shfl_xor(v2, st); const int oi2 = __shfl_xor(i2, st);
        merge2(v1, i1, v2, i2, o1, oi1, o2, oi2);
    }
    // near-tie flag: any 3rd logit within TAU of v2?
    int cnt = 0;
    #pragma unroll
    for (int n = 0; n < 4; ++n) cnt += (v[n] > v2 - TAU) ? 1 : 0;
    cnt += __shfl_xor(cnt, 1);
    cnt += __shfl_xor(cnt, 2);
    cnt += __shfl_xor(cnt, 4);
    cnt += __shfl_xor(cnt, 8);

    const int T = tokBase + m * 16 + kg * 4 + q;
    if (rl == 0 && cnt > 2) {
        const unsigned int pos = atomicAdd(flagCnt, 1u);
        if (pos < TOKENS) flagList[pos] = T;
    }
    const float ex = expf(v2 - v1);      // <= 1
    const float w1 = 1.f / (1.f + ex);
    const float w2 = ex * w1;
    const int e0 = rl * 4;
    float4 o;
    o.x = (e0 + 0 == i1) ? w1 : ((e0 + 0 == i2) ? w2 : 0.f);
    o.y = (e0 + 1 == i1) ? w1 : ((e0 + 1 == i2) ? w2 : 0.f);
    o.z = (e0 + 2 == i1) ? w1 : ((e0 + 2 == i2) ? w2 : 0.f);
    o.w = (e0 + 3 == i1) ? w1 : ((e0 + 3 == i2) ? w2 : 0.f);
    *(float4*)(Out + (size_t)T * 64 + e0) = o;
}

// ---- kernel 3: exact fp32 rescue for near-tie tokens ----
__launch_bounds__(64)
__global__ void rescue_kernel(const float* __restrict__ X,
                              const float* __restrict__ W,
                              const float* __restrict__ Bv,
                              float* __restrict__ Out,
                              const unsigned int* __restrict__ flagCnt,
                              const int* __restrict__ flagList) {
    __shared__ float sx[DDIM];
    const int lane = threadIdx.x;
    unsigned int n = *flagCnt;
    if (n > TOKENS) n = TOKENS;
    for (unsigned int i = blockIdx.x; i < n; i += gridDim.x) {
        const int t = flagList[i];
        __syncthreads();
        #pragma unroll
        for (int k = 0; k < 4; ++k)
            ((float4*)sx)[lane + 64 * k] =
                ((const float4*)(X + (size_t)t * DDIM))[lane + 64 * k];
        __syncthreads();
        float acc = Bv[lane];
        const float* wr = W + (size_t)lane * DDIM;
        #pragma unroll 4
        for (int d = 0; d < DDIM; d += 4) {
            const float4 wv = *(const float4*)(wr + d);
            acc = fmaf(sx[d + 0], wv.x, acc);
            acc = fmaf(sx[d + 1], wv.y, acc);
            acc = fmaf(sx[d + 2], wv.z, acc);
            acc = fmaf(sx[d + 3], wv.w, acc);
        }
        float v1 = acc, v2 = -INFINITY;
        int i1 = lane, i2 = 0x7fffffff;
        #pragma unroll
        for (int st = 1; st <= 32; st <<= 1) {
            const float o1 = __shfl_xor(v1, st); const int oi1 = __shfl_xor(i1, st);
            const float o2 = __shfl_xor(v2, st); const int oi2 = __shfl_xor(i2, st);
            merge2(v1, i1, v2, i2, o1, oi1, o2, oi2);
        }
        const float ex = expf(v2 - v1);
        const float w1 = 1.f / (1.f + ex);
        const float w2 = ex * w1;
        Out[(size_t)t * 64 + lane] = (lane == i1) ? w1 : ((lane == i2) ? w2 : 0.f);
    }
}

extern "C" void kernel_launch(void* const* d_in, const int* in_sizes, int n_in,
                              void* d_out, int out_size, void* d_ws, size_t ws_size,
                              hipStream_t stream) {
    const float* X  = (const float*)d_in[0];   // [32768, 1024]
    const float* W  = (const float*)d_in[1];   // [64, 1024]
    const float* Bv = (const float*)d_in[2];   // [64]
    float* Out = (float*)d_out;                // [32768, 64]

    unsigned char* ws = (unsigned char*)d_ws;
    unsigned int* cnt  = (unsigned int*)(ws + WS_CNT_OFF);
    int*          list = (int*)(ws + WS_LIST_OFF);
    unsigned int* Whi  = (unsigned int*)(ws + WS_WHI_OFF);
    unsigned int* Wlo  = (unsigned int*)(ws + WS_WLO_OFF);

    hipMemsetAsync(cnt, 0, 4, stream);
    hipLaunchKernelGGL(pack_w_kernel, dim3(32), dim3(256), 0, stream, W, Whi, Wlo);
    hipLaunchKernelGGL(router_mfma, dim3(TOKENS / 32), dim3(512), 0, stream,
                       X, Whi, Wlo, Bv, Out, cnt, list);
    hipLaunchKernelGGL(rescue_kernel, dim3(512), dim3(64), 0, stream,
                       X, W, Bv, Out, cnt, list);
}